// Round 15
// baseline (312.893 us; speedup 1.0000x reference)
//
#include <hip/hip_runtime.h>
#include <hip/hip_fp16.h>

#define NNODE 100000
#define NEDGE 1600000
#define NBUCK 196      // ceil(100000/512)
#define BSH 9          // 512 nodes per bucket
#define PCH 8192       // edges per partition block
#define CAP 9216       // fixed bucket capacity (mean 8163 + 11.6 sigma)

typedef _Float16 f16x8 __attribute__((ext_vector_type(8)));
typedef float f32x4 __attribute__((ext_vector_type(4)));

// ============ CSR build (batched over 3 edge types via blockIdx.y) ============

// Phase A: partition into fixed-capacity dst-bucket streams via per-block LDS
// counting sort; 4x-replicated count histogram, linear sBid flush, 512 threads.
__global__ __launch_bounds__(512) void partition_kernel(
    const int* __restrict__ s0, const int* __restrict__ s1, const int* __restrict__ s2,
    const int* __restrict__ d0, const int* __restrict__ d1, const int* __restrict__ d2,
    int* __restrict__ bc, int* __restrict__ pairs) {
    int y = blockIdx.y;
    const int* src = (y == 0) ? s0 : (y == 1) ? s1 : s2;
    const int* dst = (y == 0) ? d0 : (y == 1) ? d1 : d2;
    int* bcur = bc + y * 256;
    int* pr = pairs + (size_t)y * (NBUCK * CAP);

    __shared__ int sCnt4[4][NBUCK];      // replicated count histogram
    __shared__ int sCur[NBUCK];          // local cursor
    __shared__ int sDelta[NBUCK];        // globalBase - localStart
    __shared__ int sScan[256];
    __shared__ int sSort[PCH];           // bucket-sorted packed pairs (32 KB)
    __shared__ unsigned char sBid[PCH];  // bucket id per slot (8 KB)
    int t = threadIdx.x;
    for (int i = t; i < 4 * NBUCK; i += 512) sCnt4[0][i] = 0;
    __syncthreads();
    int c0 = blockIdx.x * PCH;
    int cend = min(c0 + PCH, NEDGE);
    int nblk = cend - c0;
    // pass 1: count (4 replicated copies; group = 2 waves)
    int* myCnt = sCnt4[(t >> 7) & 3];
    for (int e = c0 + t; e < cend; e += 512)
        atomicAdd(&myCnt[dst[e] >> BSH], 1);
    __syncthreads();
    // merge + scan 196 counts
    int v = 0;
    if (t < NBUCK) v = sCnt4[0][t] + sCnt4[1][t] + sCnt4[2][t] + sCnt4[3][t];
    if (t < 256) sScan[t] = v;
    __syncthreads();
    for (int off = 1; off < 256; off <<= 1) {
        int a = (t < 256) ? sScan[t] : 0;
        int b = (t >= off && t < 256) ? sScan[t - off] : 0;
        __syncthreads();
        if (t < 256) sScan[t] = a + b;
        __syncthreads();
    }
    if (t < NBUCK) {
        int excl = sScan[t] - v;
        sCur[t] = excl;           // local cursor
        int gb = v ? atomicAdd(&bcur[t], v) : 0;
        sDelta[t] = gb - excl;
    }
    __syncthreads();
    // pass 2: place into LDS sorted by bucket
    for (int e = c0 + t; e < cend; e += 512) {
        int d = dst[e];
        int b = d >> BSH;
        int slot = atomicAdd(&sCur[b], 1);
        sSort[slot] = ((d & 511) << 17) | src[e];
        sBid[slot] = (unsigned char)b;
    }
    __syncthreads();
    // flush: consecutive slots -> consecutive global within each run
    for (int i = t; i < nblk; i += 512)
        pr[sDelta[sBid[i]] + i] = sSort[i];
}

// Phase B: per-bucket CSR finalize — fully in LDS: load+histogram, scan,
// LDS->LDS cursor scatter, then LINEAR coalesced flush.
__global__ __launch_bounds__(512) void bucket_csr_kernel(const int* __restrict__ bc,
                                                         const int* __restrict__ pairs,
                                                         int2* __restrict__ rowptr2,
                                                         int* __restrict__ ssrc) {
    int y = blockIdx.y;
    pairs += (size_t)y * (NBUCK * CAP);
    rowptr2 += (size_t)y * NNODE;
    ssrc += (size_t)y * (NBUCK * CAP);

    __shared__ int sIn[CAP];    // 36 KB
    __shared__ int sOut[CAP];   // 36 KB
    __shared__ int cnt[512];
    __shared__ int cur[512];
    __shared__ int s1[512];
    int b = blockIdx.x;
    int t = threadIdx.x;
    int node0 = b << BSH;
    int start = b * CAP;
    int end = bc[y * 256 + b];   // final cursor = start + bucket count
    int m = end - start;

    cnt[t] = 0;
    __syncthreads();
    for (int i = t; i < m; i += 512) {
        int p = pairs[start + i];
        sIn[i] = p;
        atomicAdd(&cnt[p >> 17], 1);
    }
    __syncthreads();
    int v = cnt[t];
    s1[t] = v;
    __syncthreads();
    for (int off = 1; off < 512; off <<= 1) {
        int a = s1[t];
        int c = (t >= off) ? s1[t - off] : 0;
        __syncthreads();
        s1[t] = a + c;
        __syncthreads();
    }
    int eb = s1[t] - v;  // local exclusive base
    cur[t] = eb;
    if (node0 + t < NNODE) rowptr2[node0 + t] = make_int2(start + eb, start + eb + v);
    __syncthreads();
    for (int i = t; i < m; i += 512) {
        int p = sIn[i];
        int pos = atomicAdd(&cur[p >> 17], 1);
        sOut[pos] = p & 0x1FFFF;
    }
    __syncthreads();
    for (int i = t; i < m; i += 512)
        ssrc[start + i] = sOut[i];
}

// ============ gather-mean (batched over up to 3 passes via blockIdx.y) ============
// Wave per dst node, eighth-wave per edge; lane-resident ssrc + shuffle broadcast;
// degree-proportional work: 8-edge groups, wave-uniform branches on rem,
// masks only for the single partial group; packed fp16 accumulation.
__device__ __forceinline__ void gather_body(const __half* __restrict__ x,
                                            const int2* __restrict__ rowptr2,
                                            const int* __restrict__ ssrc,
                                            __half* __restrict__ out) {
    int wid = (blockIdx.x * 256 + threadIdx.x) >> 6;
    int lane = threadIdx.x & 63;
    if (wid >= NNODE) return;
    int ee = lane >> 3;             // edge slot within group: 0..7
    unsigned fo = (lane & 7) << 3;  // feature octet base (8 halves = 16B)
    int2 se = rowptr2[wid];
    int start = se.x;
    int deg = se.y - se.x;
    __half2 h0 = __float2half2_rn(0.f), h1 = h0, h2 = h0, h3 = h0;
    __half2 one = __float2half2_rn(1.f), zero = __float2half2_rn(0.f);
    for (int base = 0; base < deg; base += 64) {
        int rem = min(deg - base, 64);
        int sv = (lane < rem) ? ssrc[start + base + lane] : 0;
        int fg = rem >> 3;          // full 8-edge groups (wave-uniform)
        int w = 0;
        // 4-group unrolled chunk: 4 independent loads in flight, no masks
        for (; w + 4 <= fg; w += 4) {
            int i0 = (w << 3) + ee;
            unsigned v0 = (unsigned)__shfl(sv, i0);
            unsigned v1 = (unsigned)__shfl(sv, i0 + 8);
            unsigned v2 = (unsigned)__shfl(sv, i0 + 16);
            unsigned v3 = (unsigned)__shfl(sv, i0 + 24);
            uint4 r0 = *(const uint4*)(x + ((v0 << 6) + fo));
            uint4 r1 = *(const uint4*)(x + ((v1 << 6) + fo));
            uint4 r2 = *(const uint4*)(x + ((v2 << 6) + fo));
            uint4 r3 = *(const uint4*)(x + ((v3 << 6) + fo));
            h0 = __hadd2(h0, *(__half2*)&r0.x);
            h1 = __hadd2(h1, *(__half2*)&r0.y);
            h2 = __hadd2(h2, *(__half2*)&r0.z);
            h3 = __hadd2(h3, *(__half2*)&r0.w);
            h0 = __hadd2(h0, *(__half2*)&r1.x);
            h1 = __hadd2(h1, *(__half2*)&r1.y);
            h2 = __hadd2(h2, *(__half2*)&r1.z);
            h3 = __hadd2(h3, *(__half2*)&r1.w);
            h0 = __hadd2(h0, *(__half2*)&r2.x);
            h1 = __hadd2(h1, *(__half2*)&r2.y);
            h2 = __hadd2(h2, *(__half2*)&r2.z);
            h3 = __hadd2(h3, *(__half2*)&r2.w);
            h0 = __hadd2(h0, *(__half2*)&r3.x);
            h1 = __hadd2(h1, *(__half2*)&r3.y);
            h2 = __hadd2(h2, *(__half2*)&r3.z);
            h3 = __hadd2(h3, *(__half2*)&r3.w);
        }
        // remaining full groups, unmasked
        for (; w < fg; ++w) {
            int i0 = (w << 3) + ee;
            unsigned v0 = (unsigned)__shfl(sv, i0);
            uint4 r0 = *(const uint4*)(x + ((v0 << 6) + fo));
            h0 = __hadd2(h0, *(__half2*)&r0.x);
            h1 = __hadd2(h1, *(__half2*)&r0.y);
            h2 = __hadd2(h2, *(__half2*)&r0.z);
            h3 = __hadd2(h3, *(__half2*)&r0.w);
        }
        // single partial group (if rem not multiple of 8), masked
        if (rem & 7) {
            int i0 = (fg << 3) + ee;
            unsigned v0 = (unsigned)__shfl(sv, i0);
            __half2 m0 = (i0 < rem) ? one : zero;
            uint4 r0 = *(const uint4*)(x + ((v0 << 6) + fo));
            h0 = __hfma2(m0, *(__half2*)&r0.x, h0);
            h1 = __hfma2(m0, *(__half2*)&r0.y, h1);
            h2 = __hfma2(m0, *(__half2*)&r0.z, h2);
            h3 = __hfma2(m0, *(__half2*)&r0.w, h3);
        }
    }
#define RED8(hh) { \
        int u_ = *(int*)&hh; int r_; \
        r_ = __shfl_xor(u_, 8);  hh = __hadd2(hh, *(__half2*)&r_); u_ = *(int*)&hh; \
        r_ = __shfl_xor(u_, 16); hh = __hadd2(hh, *(__half2*)&r_); u_ = *(int*)&hh; \
        r_ = __shfl_xor(u_, 32); hh = __hadd2(hh, *(__half2*)&r_); }
    RED8(h0) RED8(h1) RED8(h2) RED8(h3)
#undef RED8
    if (ee == 0) {
        float scale = 1.0f / fmaxf((float)deg, 1.0f);
        float2 f0 = __half22float2(h0), f1 = __half22float2(h1);
        float2 f2 = __half22float2(h2), f3 = __half22float2(h3);
        uint4 w;
        *(__half2*)&w.x = __floats2half2_rn(f0.x * scale, f0.y * scale);
        *(__half2*)&w.y = __floats2half2_rn(f1.x * scale, f1.y * scale);
        *(__half2*)&w.z = __floats2half2_rn(f2.x * scale, f2.y * scale);
        *(__half2*)&w.w = __floats2half2_rn(f3.x * scale, f3.y * scale);
        *(uint4*)(out + (((unsigned)wid << 6) + fo)) = w;
    }
}

__global__ __launch_bounds__(256) void gather3_kernel(
    const __half* __restrict__ x0, const __half* __restrict__ x1, const __half* __restrict__ x2,
    const int2* __restrict__ rp0, const int2* __restrict__ rp1, const int2* __restrict__ rp2,
    const int* __restrict__ ss0, const int* __restrict__ ss1, const int* __restrict__ ss2,
    __half* __restrict__ o0, __half* __restrict__ o1, __half* __restrict__ o2) {
    int y = blockIdx.y;
    if (y == 0) gather_body(x0, rp0, ss0, o0);
    else if (y == 1) gather_body(x1, rp1, ss1, o1);
    else gather_body(x2, rp2, ss2, o2);
}

__global__ __launch_bounds__(256) void gather2_kernel(
    const __half* __restrict__ x0, const __half* __restrict__ x1,
    const int2* __restrict__ rp0, const int2* __restrict__ rp1,
    const int* __restrict__ ss0, const int* __restrict__ ss1,
    __half* __restrict__ o0, __half* __restrict__ o1) {
    int y = blockIdx.y;
    if (y == 0) gather_body(x0, rp0, ss0, o0);
    else gather_body(x1, rp1, ss1, o1);
}

// ============ weight prep: fp16 W^T (+ summed wr/biases) + cursor init ============
__global__ __launch_bounds__(256) void wprep_kernel(
    const float* __restrict__ writes_wl, const float* __restrict__ cites_wl,
    const float* __restrict__ writes_wr, const float* __restrict__ cites_wr,
    const float* __restrict__ wb_wl, const float* __restrict__ wb_wr,
    const float* __restrict__ winA_w, const float* __restrict__ winP_w,
    const float* __restrict__ lin_w,
    const float* __restrict__ writes_bl, const float* __restrict__ cites_bl,
    __half* __restrict__ wtP0, __half* __restrict__ wtP1, __half* __restrict__ wtA,
    __half* __restrict__ wtPJA, __half* __restrict__ wtPJP, __half* __restrict__ wtLIN,
    float* __restrict__ biasP, int* __restrict__ bcur) {
    int i = blockIdx.x * 256 + threadIdx.x;
    if (i < 24576) {                       // paper combine W^T [64][192] x 2 layers
        int l = i / 12288, j = i % 12288;
        int n = j / 192, k = j % 192;
        float v;
        if (k < 64) v = writes_wl[l * 4096 + k * 64 + n];
        else if (k < 128) v = cites_wl[l * 4096 + (k - 64) * 64 + n];
        else v = writes_wr[l * 4096 + (k - 128) * 64 + n] +
                 cites_wr[l * 4096 + (k - 128) * 64 + n];
        (l ? wtP1 : wtP0)[n * 192 + k] = __float2half(v);
    } else if (i < 32768) {                // author combine W^T [64][128], layer 0
        int j = i - 24576;
        int n = j / 128, k = j % 128;
        float v = (k < 64) ? wb_wl[k * 64 + n] : wb_wr[(k - 64) * 64 + n];
        wtA[n * 128 + k] = __float2half(v);
    } else if (i < 36864) {                // proj author W^T [64][64]
        int j = i - 32768;
        wtPJA[j] = __float2half(winA_w[(j % 64) * 64 + j / 64]);
    } else if (i < 40960) {                // proj paper W^T [64][64]
        int j = i - 36864;
        wtPJP[j] = __float2half(winP_w[(j % 64) * 64 + j / 64]);
    } else if (i < 41984) {                // lin W^T [16][64]
        int j = i - 40960;
        wtLIN[j] = __float2half(lin_w[(j % 64) * 16 + j / 64]);
    } else if (i < 42112) {                // summed paper biases, 2 layers
        int j = i - 41984;
        biasP[j] = writes_bl[j] + cites_bl[j];
    } else if (i < 42880) {                // partition cursors: bucket b starts at b*CAP
        int j = i - 42112;
        bcur[j] = (j & 255) * CAP;
    }
}

// ============ MFMA node-GEMMs: wave = 16 nodes, no LDS ============
__device__ inline f16x8 cvt8(const float* p) {
    float4 a = *(const float4*)p, b = *(const float4*)(p + 4);
    f16x8 r;
    r[0] = (_Float16)a.x; r[1] = (_Float16)a.y; r[2] = (_Float16)a.z; r[3] = (_Float16)a.w;
    r[4] = (_Float16)b.x; r[5] = (_Float16)b.y; r[6] = (_Float16)b.z; r[7] = (_Float16)b.w;
    return r;
}

// batched projection: y=0 authors, y=1 papers
__global__ __launch_bounds__(256) void proj_mfma(const float* __restrict__ xd0,
                                                 const float* __restrict__ xc0,
                                                 const float* __restrict__ xd1,
                                                 const float* __restrict__ xc1,
                                                 const __half* __restrict__ wt0,
                                                 const __half* __restrict__ wt1,
                                                 const float* __restrict__ b0,
                                                 const float* __restrict__ b1,
                                                 __half* __restrict__ o0,
                                                 __half* __restrict__ o1) {
    int yb = blockIdx.y;
    const float* xd = yb ? xd1 : xd0;
    const float* xc = yb ? xc1 : xc0;
    const __half* wt = yb ? wt1 : wt0;
    const float* bias = yb ? b1 : b0;
    __half* out = yb ? o1 : o0;
    int wid = (blockIdx.x * 256 + threadIdx.x) >> 6;
    if (wid >= NNODE / 16) return;
    int lane = threadIdx.x & 63;
    int row = lane & 15, kq = lane >> 4;
    int node0 = wid << 4;
    f16x8 af0 = cvt8(xd + (size_t)(node0 + row) * 32 + kq * 8);
    f16x8 af1 = cvt8(xc + (size_t)(node0 + row) * 32 + kq * 8);
#pragma unroll
    for (int nt = 0; nt < 4; ++nt) {
        int col = nt * 16 + row;
        const __half* wp = wt + (size_t)col * 64 + kq * 8;
        f32x4 acc = {0.f, 0.f, 0.f, 0.f};
        acc = __builtin_amdgcn_mfma_f32_16x16x32_f16(af0, *(const f16x8*)(wp), acc, 0, 0, 0);
        acc = __builtin_amdgcn_mfma_f32_16x16x32_f16(af1, *(const f16x8*)(wp + 32), acc, 0, 0, 0);
        float b = bias[col];
#pragma unroll
        for (int r = 0; r < 4; ++r)
            out[((size_t)(node0 + kq * 4 + r) << 6) + col] = __float2half(fmaxf(acc[r] + b, 0.f));
    }
}

template <int NSEG>
__device__ __forceinline__ void combine_body(const __half* __restrict__ a0,
                                             const __half* __restrict__ a1,
                                             const __half* __restrict__ a2,
                                             const __half* __restrict__ wt,
                                             const float* __restrict__ bias,
                                             __half* __restrict__ out) {
    int wid = (blockIdx.x * 256 + threadIdx.x) >> 6;
    if (wid >= NNODE / 16) return;
    int lane = threadIdx.x & 63;
    int row = lane & 15, kq = lane >> 4;
    int node0 = wid << 4;
    const int K = NSEG * 64;
    const __half* as[3] = {a0, a1, a2};
    f16x8 af[2 * NSEG];
#pragma unroll
    for (int s = 0; s < NSEG; ++s) {
        const __half* p = as[s] + ((size_t)(node0 + row) << 6) + kq * 8;
        af[2 * s] = *(const f16x8*)(p);
        af[2 * s + 1] = *(const f16x8*)(p + 32);
    }
#pragma unroll
    for (int nt = 0; nt < 4; ++nt) {
        int col = nt * 16 + row;
        const __half* wp = wt + (size_t)col * K + kq * 8;
        f32x4 acc = {0.f, 0.f, 0.f, 0.f};
#pragma unroll
        for (int t = 0; t < 2 * NSEG; ++t)
            acc = __builtin_amdgcn_mfma_f32_16x16x32_f16(af[t], *(const f16x8*)(wp + t * 32), acc, 0, 0, 0);
        float b = bias[col];
#pragma unroll
        for (int r = 0; r < 4; ++r)
            out[((size_t)(node0 + kq * 4 + r) << 6) + col] = __float2half(acc[r] + b);
    }
}

// L0 dual combine: y=0 papers (3-seg), y=1 authors (2-seg)
__global__ __launch_bounds__(256) void combine_dual(
    const __half* __restrict__ pm0, const __half* __restrict__ pm1, const __half* __restrict__ py,
    const __half* __restrict__ am0, const __half* __restrict__ ay,
    const __half* __restrict__ wtP, const __half* __restrict__ wtA,
    const float* __restrict__ bP, const float* __restrict__ bA,
    __half* __restrict__ oP, __half* __restrict__ oA) {
    if (blockIdx.y == 0) combine_body<3>(pm0, pm1, py, wtP, bP, oP);
    else combine_body<2>(am0, ay, nullptr, wtA, bA, oA);
}

// L1 combine fused with final projection: y_p2 tile staged in per-wave LDS,
// re-read as A-fragments, 2 MFMAs with lin W^T -> d_out fp32 directly.
__global__ __launch_bounds__(256) void combine3_final_kernel(
    const __half* __restrict__ a0, const __half* __restrict__ a1, const __half* __restrict__ a2,
    const __half* __restrict__ wt, const float* __restrict__ bias,
    const __half* __restrict__ wtLIN, const float* __restrict__ linb,
    float* __restrict__ out) {
    __shared__ __half sTile[4][16][64];   // per-wave y_p2 tile (8 KB)
    int wid = (blockIdx.x * 256 + threadIdx.x) >> 6;
    if (wid >= NNODE / 16) return;
    int wv = (threadIdx.x >> 6) & 3;
    int lane = threadIdx.x & 63;
    int row = lane & 15, kq = lane >> 4;
    int node0 = wid << 4;
    const __half* as[3] = {a0, a1, a2};
    f16x8 af[6];
#pragma unroll
    for (int s = 0; s < 3; ++s) {
        const __half* p = as[s] + ((size_t)(node0 + row) << 6) + kq * 8;
        af[2 * s] = *(const f16x8*)(p);
        af[2 * s + 1] = *(const f16x8*)(p + 32);
    }
#pragma unroll
    for (int nt = 0; nt < 4; ++nt) {
        int col = nt * 16 + row;
        const __half* wp = wt + (size_t)col * 192 + kq * 8;
        f32x4 acc = {0.f, 0.f, 0.f, 0.f};
#pragma unroll
        for (int t = 0; t < 6; ++t)
            acc = __builtin_amdgcn_mfma_f32_16x16x32_f16(af[t], *(const f16x8*)(wp + t * 32), acc, 0, 0, 0);
        float b = bias[col];
#pragma unroll
        for (int r = 0; r < 4; ++r)
            sTile[wv][kq * 4 + r][col] = __float2half(acc[r] + b);
    }
    // re-read own tile as A-fragments (wave-local LDS dependency)
    f16x8 y0 = *(const f16x8*)(&sTile[wv][row][kq * 8]);
    f16x8 y1 = *(const f16x8*)(&sTile[wv][row][kq * 8 + 32]);
    const __half* wl = wtLIN + (size_t)row * 64 + kq * 8;
    f32x4 acc = {0.f, 0.f, 0.f, 0.f};
    acc = __builtin_amdgcn_mfma_f32_16x16x32_f16(y0, *(const f16x8*)(wl), acc, 0, 0, 0);
    acc = __builtin_amdgcn_mfma_f32_16x16x32_f16(y1, *(const f16x8*)(wl + 32), acc, 0, 0, 0);
    float b = linb[row];
#pragma unroll
    for (int r = 0; r < 4; ++r)
        out[(size_t)(node0 + kq * 4 + r) * 16 + row] = acc[r] + b;
}

extern "C" void kernel_launch(void* const* d_in, const int* in_sizes, int n_in,
                              void* d_out, int out_size, void* d_ws, size_t ws_size,
                              hipStream_t stream) {
    (void)in_sizes; (void)n_in; (void)out_size; (void)ws_size;
    const float* xda = (const float*)d_in[0];
    const float* xca = (const float*)d_in[1];
    const float* xdp = (const float*)d_in[2];
    const float* xcp = (const float*)d_in[3];
    const float* winA_w = (const float*)d_in[4];
    const float* winA_b = (const float*)d_in[5];
    const float* winP_w = (const float*)d_in[6];
    const float* winP_b = (const float*)d_in[7];
    const float* writes_wl = (const float*)d_in[8];
    const float* writes_bl = (const float*)d_in[9];
    const float* writes_wr = (const float*)d_in[10];
    const float* wb_wl = (const float*)d_in[11];
    const float* wb_bl = (const float*)d_in[12];
    const float* wb_wr = (const float*)d_in[13];
    const float* cites_wl = (const float*)d_in[14];
    const float* cites_bl = (const float*)d_in[15];
    const float* cites_wr = (const float*)d_in[16];
    const float* lin_w = (const float*)d_in[17];
    const float* lin_b = (const float*)d_in[18];
    const int* w_src = (const int*)d_in[19];
    const int* w_dst = (const int*)d_in[20];
    const int* b_src = (const int*)d_in[21];
    const int* b_dst = (const int*)d_in[22];
    const int* c_src = (const int*)d_in[23];
    const int* c_dst = (const int*)d_in[24];

    const size_t NF = (size_t)NNODE * 64;
    const size_t BUK = (size_t)NBUCK * CAP;   // padded slots per edge type
    __half* B0 = (__half*)d_ws;      // y_a0 -> L1 mean_writes -> y_p2
    __half* B1 = B0 + NF;            // y_p0 -> L1 mean_cites
    __half* B2 = B1 + NF;            // L0 mean_writes -> y_p1
    __half* B3 = B2 + NF;            // L0 mean_cites
    __half* B4 = B3 + NF;            // L0 mean_wb -> y_a1

    __half* wtP0 = B4 + NF;          // 12288
    __half* wtP1 = wtP0 + 12288;     // 12288
    __half* wtA = wtP1 + 12288;      // 8192
    __half* wtPJA = wtA + 8192;      // 4096
    __half* wtPJP = wtPJA + 4096;    // 4096
    __half* wtLIN = wtPJP + 4096;    // 1024
    float* biasP = (float*)(wtLIN + 1024);  // 128

    int* ip = (int*)(biasP + 128);
    int2* rp2 = (int2*)ip;               // 3 * NNODE int2
    int* bcur = (int*)(rp2 + 3 * NNODE); // 3 * 256
    int* ssrc = bcur + 3 * 256;          // 3 * BUK
    int* pairs = (int*)B2;               // CSR-build-only alias (21.7MB < 38.4MB)

    const int GB = (NNODE * 64) / 256;      // 25000 (wave per node)
    const int MB = (NNODE / 16 + 3) / 4;    // 1563 (wave per 16 nodes)
    const int PB = (NEDGE + PCH - 1) / PCH; // 196

    // ---- weight prep (+cursor init) + CSR build ----
    wprep_kernel<<<168, 256, 0, stream>>>(writes_wl, cites_wl, writes_wr, cites_wr,
                                          wb_wl, wb_wr, winA_w, winP_w, lin_w,
                                          writes_bl, cites_bl,
                                          wtP0, wtP1, wtA, wtPJA, wtPJP, wtLIN, biasP, bcur);
    partition_kernel<<<dim3(PB, 3), 512, 0, stream>>>(w_src, c_src, b_src,
                                                      w_dst, c_dst, b_dst, bcur, pairs);
    bucket_csr_kernel<<<dim3(NBUCK, 3), 512, 0, stream>>>(bcur, pairs, rp2, ssrc);

    const int2* rp_w = rp2;
    const int2* rp_c = rp2 + NNODE;
    const int2* rp_b = rp2 + 2 * NNODE;
    const int* ss_w = ssrc;
    const int* ss_c = ssrc + BUK;
    const int* ss_b = ssrc + 2 * BUK;

    // ---- input projections (batched) ----
    proj_mfma<<<dim3(MB, 2), 256, 0, stream>>>(xda, xca, xdp, xcp,
                                               wtPJA, wtPJP, winA_b, winP_b, B0, B1);

    // ---- layer 0: 3 gathers in one dispatch (cites+wb share table B1) ----
    gather3_kernel<<<dim3(GB, 3), 256, 0, stream>>>(B0, B1, B1,
                                                    rp_w, rp_c, rp_b,
                                                    ss_w, ss_c, ss_b,
                                                    B2, B3, B4);
    combine_dual<<<dim3(MB, 2), 256, 0, stream>>>(B2, B3, B1, B4, B0,
                                                  wtP0, wtA, biasP, wb_bl, B2, B4);

    // ---- layer 1 (author update is dead code in the reference: skipped) ----
    gather2_kernel<<<dim3(GB, 2), 256, 0, stream>>>(B4, B2,
                                                    rp_w, rp_c,
                                                    ss_w, ss_c,
                                                    B0, B1);
    // L1 combine + final projection fused -> d_out
    combine3_final_kernel<<<MB, 256, 0, stream>>>(B0, B1, B2, wtP1, biasP + 64,
                                                  wtLIN, lin_b, (float*)d_out);
}

// Round 16
// 288.422 us; speedup vs baseline: 1.0848x; 1.0848x over previous
//
#include <hip/hip_runtime.h>
#include <hip/hip_fp16.h>

#define NNODE 100000
#define NEDGE 1600000
#define NBUCK 196      // ceil(100000/512)
#define BSH 9          // 512 nodes per bucket
#define PCH 8192       // edges per partition block
#define CAP 9216       // fixed bucket capacity (mean 8163 + 11.6 sigma)

typedef _Float16 f16x8 __attribute__((ext_vector_type(8)));
typedef float f32x4 __attribute__((ext_vector_type(4)));

// ============ CSR build (batched over 3 edge types via blockIdx.y) ============

// Phase A: partition into fixed-capacity dst-bucket streams via per-block LDS
// counting sort; 4x-replicated count histogram, linear sBid flush, 512 threads.
__global__ __launch_bounds__(512) void partition_kernel(
    const int* __restrict__ s0, const int* __restrict__ s1, const int* __restrict__ s2,
    const int* __restrict__ d0, const int* __restrict__ d1, const int* __restrict__ d2,
    int* __restrict__ bc, int* __restrict__ pairs) {
    int y = blockIdx.y;
    const int* src = (y == 0) ? s0 : (y == 1) ? s1 : s2;
    const int* dst = (y == 0) ? d0 : (y == 1) ? d1 : d2;
    int* bcur = bc + y * 256;
    int* pr = pairs + (size_t)y * (NBUCK * CAP);

    __shared__ int sCnt4[4][NBUCK];      // replicated count histogram
    __shared__ int sCur[NBUCK];          // local cursor
    __shared__ int sDelta[NBUCK];        // globalBase - localStart
    __shared__ int sScan[256];
    __shared__ int sSort[PCH];           // bucket-sorted packed pairs (32 KB)
    __shared__ unsigned char sBid[PCH];  // bucket id per slot (8 KB)
    int t = threadIdx.x;
    for (int i = t; i < 4 * NBUCK; i += 512) sCnt4[0][i] = 0;
    __syncthreads();
    int c0 = blockIdx.x * PCH;
    int cend = min(c0 + PCH, NEDGE);
    int nblk = cend - c0;
    // pass 1: count (4 replicated copies; group = 2 waves)
    int* myCnt = sCnt4[(t >> 7) & 3];
    for (int e = c0 + t; e < cend; e += 512)
        atomicAdd(&myCnt[dst[e] >> BSH], 1);
    __syncthreads();
    // merge + scan 196 counts
    int v = 0;
    if (t < NBUCK) v = sCnt4[0][t] + sCnt4[1][t] + sCnt4[2][t] + sCnt4[3][t];
    if (t < 256) sScan[t] = v;
    __syncthreads();
    for (int off = 1; off < 256; off <<= 1) {
        int a = (t < 256) ? sScan[t] : 0;
        int b = (t >= off && t < 256) ? sScan[t - off] : 0;
        __syncthreads();
        if (t < 256) sScan[t] = a + b;
        __syncthreads();
    }
    if (t < NBUCK) {
        int excl = sScan[t] - v;
        sCur[t] = excl;           // local cursor
        int gb = v ? atomicAdd(&bcur[t], v) : 0;
        sDelta[t] = gb - excl;
    }
    __syncthreads();
    // pass 2: place into LDS sorted by bucket
    for (int e = c0 + t; e < cend; e += 512) {
        int d = dst[e];
        int b = d >> BSH;
        int slot = atomicAdd(&sCur[b], 1);
        sSort[slot] = ((d & 511) << 17) | src[e];
        sBid[slot] = (unsigned char)b;
    }
    __syncthreads();
    // flush: consecutive slots -> consecutive global within each run
    for (int i = t; i < nblk; i += 512)
        pr[sDelta[sBid[i]] + i] = sSort[i];
}

// Phase B: per-bucket CSR finalize — fully in LDS: load+histogram, scan,
// LDS->LDS cursor scatter, then LINEAR coalesced flush.
__global__ __launch_bounds__(512) void bucket_csr_kernel(const int* __restrict__ bc,
                                                         const int* __restrict__ pairs,
                                                         int2* __restrict__ rowptr2,
                                                         int* __restrict__ ssrc) {
    int y = blockIdx.y;
    pairs += (size_t)y * (NBUCK * CAP);
    rowptr2 += (size_t)y * NNODE;
    ssrc += (size_t)y * (NBUCK * CAP);

    __shared__ int sIn[CAP];    // 36 KB
    __shared__ int sOut[CAP];   // 36 KB
    __shared__ int cnt[512];
    __shared__ int cur[512];
    __shared__ int s1[512];
    int b = blockIdx.x;
    int t = threadIdx.x;
    int node0 = b << BSH;
    int start = b * CAP;
    int end = bc[y * 256 + b];   // final cursor = start + bucket count
    int m = end - start;

    cnt[t] = 0;
    __syncthreads();
    for (int i = t; i < m; i += 512) {
        int p = pairs[start + i];
        sIn[i] = p;
        atomicAdd(&cnt[p >> 17], 1);
    }
    __syncthreads();
    int v = cnt[t];
    s1[t] = v;
    __syncthreads();
    for (int off = 1; off < 512; off <<= 1) {
        int a = s1[t];
        int c = (t >= off) ? s1[t - off] : 0;
        __syncthreads();
        s1[t] = a + c;
        __syncthreads();
    }
    int eb = s1[t] - v;  // local exclusive base
    cur[t] = eb;
    if (node0 + t < NNODE) rowptr2[node0 + t] = make_int2(start + eb, start + eb + v);
    __syncthreads();
    for (int i = t; i < m; i += 512) {
        int p = sIn[i];
        int pos = atomicAdd(&cur[p >> 17], 1);
        sOut[pos] = p & 0x1FFFF;
    }
    __syncthreads();
    for (int i = t; i < m; i += 512)
        ssrc[start + i] = sOut[i];
}

// ============ gather-mean (batched over up to 3 passes via blockIdx.y) ============
// Wave per dst node, eighth-wave per edge; lane-resident ssrc + shuffle broadcast
// (no redundant index loads); 32-edge superwindows, 4 row loads in flight,
// fully mask-predicated (R13 max-MLP version — masked loads are latency hiding).
__device__ __forceinline__ void gather_body(const __half* __restrict__ x,
                                            const int2* __restrict__ rowptr2,
                                            const int* __restrict__ ssrc,
                                            __half* __restrict__ out) {
    int wid = (blockIdx.x * 256 + threadIdx.x) >> 6;
    int lane = threadIdx.x & 63;
    if (wid >= NNODE) return;
    int ee = lane >> 3;             // edge slot 0..7
    unsigned fo = (lane & 7) << 3;  // feature octet base (8 halves = 16B)
    int2 se = rowptr2[wid];
    int start = se.x;
    int deg = se.y - se.x;
    __half2 h0 = __float2half2_rn(0.f), h1 = h0, h2 = h0, h3 = h0;
    __half2 one = __float2half2_rn(1.f), zero = __float2half2_rn(0.f);
    for (int base = 0; base < deg; base += 64) {
        int rem = min(deg - base, 64);
        int sv = (lane < rem) ? ssrc[start + base + lane] : 0;
        int nsw = (rem + 31) >> 5;   // 32-edge superwindows
        for (int w = 0; w < nsw; ++w) {
            int i0 = (w << 5) + ee;
            int i1 = i0 + 8, i2 = i0 + 16, i3 = i0 + 24;
            unsigned v0 = (unsigned)__shfl(sv, i0);
            unsigned v1 = (unsigned)__shfl(sv, i1);
            unsigned v2 = (unsigned)__shfl(sv, i2);
            unsigned v3 = (unsigned)__shfl(sv, i3);
            __half2 m0 = (i0 < rem) ? one : zero;
            __half2 m1 = (i1 < rem) ? one : zero;
            __half2 m2 = (i2 < rem) ? one : zero;
            __half2 m3 = (i3 < rem) ? one : zero;
            uint4 r0 = *(const uint4*)(x + ((v0 << 6) + fo));
            uint4 r1 = *(const uint4*)(x + ((v1 << 6) + fo));
            uint4 r2 = *(const uint4*)(x + ((v2 << 6) + fo));
            uint4 r3 = *(const uint4*)(x + ((v3 << 6) + fo));
            h0 = __hfma2(m0, *(__half2*)&r0.x, h0);
            h1 = __hfma2(m0, *(__half2*)&r0.y, h1);
            h2 = __hfma2(m0, *(__half2*)&r0.z, h2);
            h3 = __hfma2(m0, *(__half2*)&r0.w, h3);
            h0 = __hfma2(m1, *(__half2*)&r1.x, h0);
            h1 = __hfma2(m1, *(__half2*)&r1.y, h1);
            h2 = __hfma2(m1, *(__half2*)&r1.z, h2);
            h3 = __hfma2(m1, *(__half2*)&r1.w, h3);
            h0 = __hfma2(m2, *(__half2*)&r2.x, h0);
            h1 = __hfma2(m2, *(__half2*)&r2.y, h1);
            h2 = __hfma2(m2, *(__half2*)&r2.z, h2);
            h3 = __hfma2(m2, *(__half2*)&r2.w, h3);
            h0 = __hfma2(m3, *(__half2*)&r3.x, h0);
            h1 = __hfma2(m3, *(__half2*)&r3.y, h1);
            h2 = __hfma2(m3, *(__half2*)&r3.z, h2);
            h3 = __hfma2(m3, *(__half2*)&r3.w, h3);
        }
    }
#define RED8(hh) { \
        int u_ = *(int*)&hh; int r_; \
        r_ = __shfl_xor(u_, 8);  hh = __hadd2(hh, *(__half2*)&r_); u_ = *(int*)&hh; \
        r_ = __shfl_xor(u_, 16); hh = __hadd2(hh, *(__half2*)&r_); u_ = *(int*)&hh; \
        r_ = __shfl_xor(u_, 32); hh = __hadd2(hh, *(__half2*)&r_); }
    RED8(h0) RED8(h1) RED8(h2) RED8(h3)
#undef RED8
    if (ee == 0) {
        float scale = 1.0f / fmaxf((float)deg, 1.0f);
        float2 f0 = __half22float2(h0), f1 = __half22float2(h1);
        float2 f2 = __half22float2(h2), f3 = __half22float2(h3);
        uint4 w;
        *(__half2*)&w.x = __floats2half2_rn(f0.x * scale, f0.y * scale);
        *(__half2*)&w.y = __floats2half2_rn(f1.x * scale, f1.y * scale);
        *(__half2*)&w.z = __floats2half2_rn(f2.x * scale, f2.y * scale);
        *(__half2*)&w.w = __floats2half2_rn(f3.x * scale, f3.y * scale);
        *(uint4*)(out + (((unsigned)wid << 6) + fo)) = w;
    }
}

__global__ __launch_bounds__(256) void gather3_kernel(
    const __half* __restrict__ x0, const __half* __restrict__ x1, const __half* __restrict__ x2,
    const int2* __restrict__ rp0, const int2* __restrict__ rp1, const int2* __restrict__ rp2,
    const int* __restrict__ ss0, const int* __restrict__ ss1, const int* __restrict__ ss2,
    __half* __restrict__ o0, __half* __restrict__ o1, __half* __restrict__ o2) {
    int y = blockIdx.y;
    if (y == 0) gather_body(x0, rp0, ss0, o0);
    else if (y == 1) gather_body(x1, rp1, ss1, o1);
    else gather_body(x2, rp2, ss2, o2);
}

__global__ __launch_bounds__(256) void gather2_kernel(
    const __half* __restrict__ x0, const __half* __restrict__ x1,
    const int2* __restrict__ rp0, const int2* __restrict__ rp1,
    const int* __restrict__ ss0, const int* __restrict__ ss1,
    __half* __restrict__ o0, __half* __restrict__ o1) {
    int y = blockIdx.y;
    if (y == 0) gather_body(x0, rp0, ss0, o0);
    else gather_body(x1, rp1, ss1, o1);
}

// ============ weight prep: fp16 W^T (+ summed wr/biases) + cursor init ============
__global__ __launch_bounds__(256) void wprep_kernel(
    const float* __restrict__ writes_wl, const float* __restrict__ cites_wl,
    const float* __restrict__ writes_wr, const float* __restrict__ cites_wr,
    const float* __restrict__ wb_wl, const float* __restrict__ wb_wr,
    const float* __restrict__ winA_w, const float* __restrict__ winP_w,
    const float* __restrict__ lin_w,
    const float* __restrict__ writes_bl, const float* __restrict__ cites_bl,
    __half* __restrict__ wtP0, __half* __restrict__ wtP1, __half* __restrict__ wtA,
    __half* __restrict__ wtPJA, __half* __restrict__ wtPJP, __half* __restrict__ wtLIN,
    float* __restrict__ biasP, int* __restrict__ bcur) {
    int i = blockIdx.x * 256 + threadIdx.x;
    if (i < 24576) {                       // paper combine W^T [64][192] x 2 layers
        int l = i / 12288, j = i % 12288;
        int n = j / 192, k = j % 192;
        float v;
        if (k < 64) v = writes_wl[l * 4096 + k * 64 + n];
        else if (k < 128) v = cites_wl[l * 4096 + (k - 64) * 64 + n];
        else v = writes_wr[l * 4096 + (k - 128) * 64 + n] +
                 cites_wr[l * 4096 + (k - 128) * 64 + n];
        (l ? wtP1 : wtP0)[n * 192 + k] = __float2half(v);
    } else if (i < 32768) {                // author combine W^T [64][128], layer 0
        int j = i - 24576;
        int n = j / 128, k = j % 128;
        float v = (k < 64) ? wb_wl[k * 64 + n] : wb_wr[(k - 64) * 64 + n];
        wtA[n * 128 + k] = __float2half(v);
    } else if (i < 36864) {                // proj author W^T [64][64]
        int j = i - 32768;
        wtPJA[j] = __float2half(winA_w[(j % 64) * 64 + j / 64]);
    } else if (i < 40960) {                // proj paper W^T [64][64]
        int j = i - 36864;
        wtPJP[j] = __float2half(winP_w[(j % 64) * 64 + j / 64]);
    } else if (i < 41984) {                // lin W^T [16][64]
        int j = i - 40960;
        wtLIN[j] = __float2half(lin_w[(j % 64) * 16 + j / 64]);
    } else if (i < 42112) {                // summed paper biases, 2 layers
        int j = i - 41984;
        biasP[j] = writes_bl[j] + cites_bl[j];
    } else if (i < 42880) {                // partition cursors: bucket b starts at b*CAP
        int j = i - 42112;
        bcur[j] = (j & 255) * CAP;
    }
}

// ============ MFMA node-GEMMs: wave = 16 nodes, no LDS ============
__device__ inline f16x8 cvt8(const float* p) {
    float4 a = *(const float4*)p, b = *(const float4*)(p + 4);
    f16x8 r;
    r[0] = (_Float16)a.x; r[1] = (_Float16)a.y; r[2] = (_Float16)a.z; r[3] = (_Float16)a.w;
    r[4] = (_Float16)b.x; r[5] = (_Float16)b.y; r[6] = (_Float16)b.z; r[7] = (_Float16)b.w;
    return r;
}

// batched projection: y=0 authors, y=1 papers
__global__ __launch_bounds__(256) void proj_mfma(const float* __restrict__ xd0,
                                                 const float* __restrict__ xc0,
                                                 const float* __restrict__ xd1,
                                                 const float* __restrict__ xc1,
                                                 const __half* __restrict__ wt0,
                                                 const __half* __restrict__ wt1,
                                                 const float* __restrict__ b0,
                                                 const float* __restrict__ b1,
                                                 __half* __restrict__ o0,
                                                 __half* __restrict__ o1) {
    int yb = blockIdx.y;
    const float* xd = yb ? xd1 : xd0;
    const float* xc = yb ? xc1 : xc0;
    const __half* wt = yb ? wt1 : wt0;
    const float* bias = yb ? b1 : b0;
    __half* out = yb ? o1 : o0;
    int wid = (blockIdx.x * 256 + threadIdx.x) >> 6;
    if (wid >= NNODE / 16) return;
    int lane = threadIdx.x & 63;
    int row = lane & 15, kq = lane >> 4;
    int node0 = wid << 4;
    f16x8 af0 = cvt8(xd + (size_t)(node0 + row) * 32 + kq * 8);
    f16x8 af1 = cvt8(xc + (size_t)(node0 + row) * 32 + kq * 8);
#pragma unroll
    for (int nt = 0; nt < 4; ++nt) {
        int col = nt * 16 + row;
        const __half* wp = wt + (size_t)col * 64 + kq * 8;
        f32x4 acc = {0.f, 0.f, 0.f, 0.f};
        acc = __builtin_amdgcn_mfma_f32_16x16x32_f16(af0, *(const f16x8*)(wp), acc, 0, 0, 0);
        acc = __builtin_amdgcn_mfma_f32_16x16x32_f16(af1, *(const f16x8*)(wp + 32), acc, 0, 0, 0);
        float b = bias[col];
#pragma unroll
        for (int r = 0; r < 4; ++r)
            out[((size_t)(node0 + kq * 4 + r) << 6) + col] = __float2half(fmaxf(acc[r] + b, 0.f));
    }
}

template <int NSEG>
__device__ __forceinline__ void combine_body(const __half* __restrict__ a0,
                                             const __half* __restrict__ a1,
                                             const __half* __restrict__ a2,
                                             const __half* __restrict__ wt,
                                             const float* __restrict__ bias,
                                             __half* __restrict__ out) {
    int wid = (blockIdx.x * 256 + threadIdx.x) >> 6;
    if (wid >= NNODE / 16) return;
    int lane = threadIdx.x & 63;
    int row = lane & 15, kq = lane >> 4;
    int node0 = wid << 4;
    const int K = NSEG * 64;
    const __half* as[3] = {a0, a1, a2};
    f16x8 af[2 * NSEG];
#pragma unroll
    for (int s = 0; s < NSEG; ++s) {
        const __half* p = as[s] + ((size_t)(node0 + row) << 6) + kq * 8;
        af[2 * s] = *(const f16x8*)(p);
        af[2 * s + 1] = *(const f16x8*)(p + 32);
    }
#pragma unroll
    for (int nt = 0; nt < 4; ++nt) {
        int col = nt * 16 + row;
        const __half* wp = wt + (size_t)col * K + kq * 8;
        f32x4 acc = {0.f, 0.f, 0.f, 0.f};
#pragma unroll
        for (int t = 0; t < 2 * NSEG; ++t)
            acc = __builtin_amdgcn_mfma_f32_16x16x32_f16(af[t], *(const f16x8*)(wp + t * 32), acc, 0, 0, 0);
        float b = bias[col];
#pragma unroll
        for (int r = 0; r < 4; ++r)
            out[((size_t)(node0 + kq * 4 + r) << 6) + col] = __float2half(acc[r] + b);
    }
}

// L0 dual combine: y=0 papers (3-seg), y=1 authors (2-seg)
__global__ __launch_bounds__(256) void combine_dual(
    const __half* __restrict__ pm0, const __half* __restrict__ pm1, const __half* __restrict__ py,
    const __half* __restrict__ am0, const __half* __restrict__ ay,
    const __half* __restrict__ wtP, const __half* __restrict__ wtA,
    const float* __restrict__ bP, const float* __restrict__ bA,
    __half* __restrict__ oP, __half* __restrict__ oA) {
    if (blockIdx.y == 0) combine_body<3>(pm0, pm1, py, wtP, bP, oP);
    else combine_body<2>(am0, ay, nullptr, wtA, bA, oA);
}

// L1 combine fused with final projection: y_p2 tile staged in per-wave LDS,
// re-read as A-fragments, 2 MFMAs with lin W^T -> d_out fp32 directly.
__global__ __launch_bounds__(256) void combine3_final_kernel(
    const __half* __restrict__ a0, const __half* __restrict__ a1, const __half* __restrict__ a2,
    const __half* __restrict__ wt, const float* __restrict__ bias,
    const __half* __restrict__ wtLIN, const float* __restrict__ linb,
    float* __restrict__ out) {
    __shared__ __half sTile[4][16][64];   // per-wave y_p2 tile (8 KB)
    int wid = (blockIdx.x * 256 + threadIdx.x) >> 6;
    if (wid >= NNODE / 16) return;
    int wv = (threadIdx.x >> 6) & 3;
    int lane = threadIdx.x & 63;
    int row = lane & 15, kq = lane >> 4;
    int node0 = wid << 4;
    const __half* as[3] = {a0, a1, a2};
    f16x8 af[6];
#pragma unroll
    for (int s = 0; s < 3; ++s) {
        const __half* p = as[s] + ((size_t)(node0 + row) << 6) + kq * 8;
        af[2 * s] = *(const f16x8*)(p);
        af[2 * s + 1] = *(const f16x8*)(p + 32);
    }
#pragma unroll
    for (int nt = 0; nt < 4; ++nt) {
        int col = nt * 16 + row;
        const __half* wp = wt + (size_t)col * 192 + kq * 8;
        f32x4 acc = {0.f, 0.f, 0.f, 0.f};
#pragma unroll
        for (int t = 0; t < 6; ++t)
            acc = __builtin_amdgcn_mfma_f32_16x16x32_f16(af[t], *(const f16x8*)(wp + t * 32), acc, 0, 0, 0);
        float b = bias[col];
#pragma unroll
        for (int r = 0; r < 4; ++r)
            sTile[wv][kq * 4 + r][col] = __float2half(acc[r] + b);
    }
    // re-read own tile as A-fragments (wave-local LDS dependency)
    f16x8 y0 = *(const f16x8*)(&sTile[wv][row][kq * 8]);
    f16x8 y1 = *(const f16x8*)(&sTile[wv][row][kq * 8 + 32]);
    const __half* wl = wtLIN + (size_t)row * 64 + kq * 8;
    f32x4 acc = {0.f, 0.f, 0.f, 0.f};
    acc = __builtin_amdgcn_mfma_f32_16x16x32_f16(y0, *(const f16x8*)(wl), acc, 0, 0, 0);
    acc = __builtin_amdgcn_mfma_f32_16x16x32_f16(y1, *(const f16x8*)(wl + 32), acc, 0, 0, 0);
    float b = linb[row];
#pragma unroll
    for (int r = 0; r < 4; ++r)
        out[(size_t)(node0 + kq * 4 + r) * 16 + row] = acc[r] + b;
}

extern "C" void kernel_launch(void* const* d_in, const int* in_sizes, int n_in,
                              void* d_out, int out_size, void* d_ws, size_t ws_size,
                              hipStream_t stream) {
    (void)in_sizes; (void)n_in; (void)out_size; (void)ws_size;
    const float* xda = (const float*)d_in[0];
    const float* xca = (const float*)d_in[1];
    const float* xdp = (const float*)d_in[2];
    const float* xcp = (const float*)d_in[3];
    const float* winA_w = (const float*)d_in[4];
    const float* winA_b = (const float*)d_in[5];
    const float* winP_w = (const float*)d_in[6];
    const float* winP_b = (const float*)d_in[7];
    const float* writes_wl = (const float*)d_in[8];
    const float* writes_bl = (const float*)d_in[9];
    const float* writes_wr = (const float*)d_in[10];
    const float* wb_wl = (const float*)d_in[11];
    const float* wb_bl = (const float*)d_in[12];
    const float* wb_wr = (const float*)d_in[13];
    const float* cites_wl = (const float*)d_in[14];
    const float* cites_bl = (const float*)d_in[15];
    const float* cites_wr = (const float*)d_in[16];
    const float* lin_w = (const float*)d_in[17];
    const float* lin_b = (const float*)d_in[18];
    const int* w_src = (const int*)d_in[19];
    const int* w_dst = (const int*)d_in[20];
    const int* b_src = (const int*)d_in[21];
    const int* b_dst = (const int*)d_in[22];
    const int* c_src = (const int*)d_in[23];
    const int* c_dst = (const int*)d_in[24];

    const size_t NF = (size_t)NNODE * 64;
    const size_t BUK = (size_t)NBUCK * CAP;   // padded slots per edge type
    __half* B0 = (__half*)d_ws;      // y_a0 -> L1 mean_writes -> y_p2
    __half* B1 = B0 + NF;            // y_p0 -> L1 mean_cites
    __half* B2 = B1 + NF;            // L0 mean_writes -> y_p1
    __half* B3 = B2 + NF;            // L0 mean_cites
    __half* B4 = B3 + NF;            // L0 mean_wb -> y_a1

    __half* wtP0 = B4 + NF;          // 12288
    __half* wtP1 = wtP0 + 12288;     // 12288
    __half* wtA = wtP1 + 12288;      // 8192
    __half* wtPJA = wtA + 8192;      // 4096
    __half* wtPJP = wtPJA + 4096;    // 4096
    __half* wtLIN = wtPJP + 4096;    // 1024
    float* biasP = (float*)(wtLIN + 1024);  // 128

    int* ip = (int*)(biasP + 128);
    int2* rp2 = (int2*)ip;               // 3 * NNODE int2
    int* bcur = (int*)(rp2 + 3 * NNODE); // 3 * 256
    int* ssrc = bcur + 3 * 256;          // 3 * BUK
    int* pairs = (int*)B2;               // CSR-build-only alias (21.7MB < 38.4MB)

    const int GB = (NNODE * 64) / 256;      // 25000 (wave per node)
    const int MB = (NNODE / 16 + 3) / 4;    // 1563 (wave per 16 nodes)
    const int PB = (NEDGE + PCH - 1) / PCH; // 196

    // ---- weight prep (+cursor init) + CSR build ----
    wprep_kernel<<<168, 256, 0, stream>>>(writes_wl, cites_wl, writes_wr, cites_wr,
                                          wb_wl, wb_wr, winA_w, winP_w, lin_w,
                                          writes_bl, cites_bl,
                                          wtP0, wtP1, wtA, wtPJA, wtPJP, wtLIN, biasP, bcur);
    partition_kernel<<<dim3(PB, 3), 512, 0, stream>>>(w_src, c_src, b_src,
                                                      w_dst, c_dst, b_dst, bcur, pairs);
    bucket_csr_kernel<<<dim3(NBUCK, 3), 512, 0, stream>>>(bcur, pairs, rp2, ssrc);

    const int2* rp_w = rp2;
    const int2* rp_c = rp2 + NNODE;
    const int2* rp_b = rp2 + 2 * NNODE;
    const int* ss_w = ssrc;
    const int* ss_c = ssrc + BUK;
    const int* ss_b = ssrc + 2 * BUK;

    // ---- input projections (batched) ----
    proj_mfma<<<dim3(MB, 2), 256, 0, stream>>>(xda, xca, xdp, xcp,
                                               wtPJA, wtPJP, winA_b, winP_b, B0, B1);

    // ---- layer 0: 3 gathers in one dispatch (cites+wb share table B1) ----
    gather3_kernel<<<dim3(GB, 3), 256, 0, stream>>>(B0, B1, B1,
                                                    rp_w, rp_c, rp_b,
                                                    ss_w, ss_c, ss_b,
                                                    B2, B3, B4);
    combine_dual<<<dim3(MB, 2), 256, 0, stream>>>(B2, B3, B1, B4, B0,
                                                  wtP0, wtA, biasP, wb_bl, B2, B4);

    // ---- layer 1 (author update is dead code in the reference: skipped) ----
    gather2_kernel<<<dim3(GB, 2), 256, 0, stream>>>(B4, B2,
                                                    rp_w, rp_c,
                                                    ss_w, ss_c,
                                                    B0, B1);
    // L1 combine + final projection fused -> d_out
    combine3_final_kernel<<<MB, 256, 0, stream>>>(B0, B1, B2, wtP1, biasP + 64,
                                                  wtLIN, lin_b, (float*)d_out);
}